// Round 6
// baseline (353.298 us; speedup 1.0000x reference)
//
#include <hip/hip_runtime.h>
#include <hip/hip_bf16.h>
#include <cstdint>

typedef __bf16 bf16_t;
typedef __bf16 bf16x8 __attribute__((ext_vector_type(8)));
typedef float  f32x4  __attribute__((ext_vector_type(4)));
typedef int    i32x4  __attribute__((ext_vector_type(4)));

#define MFMA16(a, b, c) __builtin_amdgcn_mfma_f32_16x16x32_bf16((a), (b), (c), 0, 0, 0)

constexpr int BB = 8, CC = 384, NHH = 6, TT = 1024;

union U8 { uint4 u; bf16_t h[8]; };
union U2 { unsigned int u; bf16_t h[2]; };
union I4B { i32x4 i; bf16x8 v; };

static __device__ __forceinline__ void gload_lds16(const void* g, void* l) {
    __builtin_amdgcn_global_load_lds((const __attribute__((address_space(1))) void*)g,
                                     (__attribute__((address_space(3))) void*)l, 16, 0, 0);
}

// load 8 consecutive fp32 -> bf16x8
static __device__ __forceinline__ bf16x8 cvt8(const float* p) {
    f32x4 a = *(const f32x4*)p, b = *(const f32x4*)(p + 4);
    U8 o;
    #pragma unroll
    for (int j = 0; j < 4; ++j) { o.h[j] = (bf16_t)a[j]; o.h[4 + j] = (bf16_t)b[j]; }
    return *(bf16x8*)&o;
}

// ---------------------------------------------------------------------------
// K1: QKV projection from fp32 inputs (cast fused). vrow fused via atomics.
// Grid dim3(16,6,8): tt=x, og=y, b=z so the 6 og-blocks of one (b,tt) have
// linear ids differing by 16 -> same XCD (id%8 == tt%8): x-tile fetched from
// HBM once, L2-hit for the other 5.
// ---------------------------------------------------------------------------
__global__ __launch_bounds__(256) void qkv_kernel(
    const float* __restrict__ x,
    const float* __restrict__ Wq,
    const float* __restrict__ Wk,
    const float* __restrict__ Wv,
    bf16_t* __restrict__ qT,
    bf16_t* __restrict__ kT,
    bf16_t* __restrict__ vm,
    float*  __restrict__ vrs)
{
    const int tt = blockIdx.x;
    const int og = blockIdx.y;        // 0,1:q  2,3:k  4,5:v  (og&1 = o-half)
    const int b  = blockIdx.z;
    const int t0 = tt * 64;
    const int tid  = threadIdx.x;
    const int lane = tid & 63;
    const int wid  = tid >> 6;
    const int quad = lane >> 4;
    const int l16  = lane & 15;

    __shared__ __align__(16) bf16_t xT[64][CC + 8];

    {
        const float* xb = x + (size_t)b * CC * TT;
        const int tq = tid & 7;
        const int cp = tid >> 3;
        #pragma unroll
        for (int pass = 0; pass < 6; ++pass) {
            const int c = (pass * 32 + cp) * 2;
            const float* r0 = xb + (size_t)c * TT + t0 + tq * 8;
            const float* r1 = r0 + TT;
            f32x4 a0 = *(const f32x4*)r0, a1 = *(const f32x4*)(r0 + 4);
            f32x4 b0 = *(const f32x4*)r1, b1 = *(const f32x4*)(r1 + 4);
            #pragma unroll
            for (int j = 0; j < 8; ++j) {
                U2 p;
                p.h[0] = (bf16_t)((j < 4) ? a0[j] : a1[j - 4]);
                p.h[1] = (bf16_t)((j < 4) ? b0[j] : b1[j - 4]);
                *(unsigned int*)&xT[tq * 8 + j][c] = p.u;
            }
        }
    }
    __syncthreads();

    const float* W = (og < 2) ? Wq : (og < 4) ? Wk : Wv;
    const int obase = (og & 1) * 192 + wid * 48;

    if (og < 4) {
        f32x4 acc[3][4];
        const f32x4 zero = {0.f, 0.f, 0.f, 0.f};
        #pragma unroll
        for (int mi = 0; mi < 3; ++mi)
            #pragma unroll
            for (int ni = 0; ni < 4; ++ni) acc[mi][ni] = zero;

        for (int k0 = 0; k0 < CC; k0 += 32) {
            bf16x8 afr[3];
            #pragma unroll
            for (int mi = 0; mi < 3; ++mi)
                afr[mi] = cvt8(W + (size_t)(obase + mi * 16 + l16) * CC + k0 + quad * 8);
            #pragma unroll
            for (int ni = 0; ni < 4; ++ni) {
                bf16x8 bfr = *(const bf16x8*)&xT[ni * 16 + l16][k0 + quad * 8];
                #pragma unroll
                for (int mi = 0; mi < 3; ++mi)
                    acc[mi][ni] = MFMA16(afr[mi], bfr, acc[mi][ni]);
            }
        }

        bf16_t* dst = (og < 2) ? qT : kT;
        #pragma unroll
        for (int mi = 0; mi < 3; ++mi)
            #pragma unroll
            for (int ni = 0; ni < 4; ++ni) {
                const int o0 = obase + mi * 16 + quad * 4;
                const int tl = t0 + ni * 16 + l16;
                U2 lo2, hi2;
                lo2.h[0] = (bf16_t)acc[mi][ni][0]; lo2.h[1] = (bf16_t)acc[mi][ni][1];
                hi2.h[0] = (bf16_t)acc[mi][ni][2]; hi2.h[1] = (bf16_t)acc[mi][ni][3];
                uint2 pk; pk.x = lo2.u; pk.y = hi2.u;
                *(uint2*)(dst + ((size_t)b * TT + tl) * CC + o0) = pk;
            }
    } else {
        f32x4 acc[4][3];
        const f32x4 zero = {0.f, 0.f, 0.f, 0.f};
        #pragma unroll
        for (int mi = 0; mi < 4; ++mi)
            #pragma unroll
            for (int ni = 0; ni < 3; ++ni) acc[mi][ni] = zero;

        for (int k0 = 0; k0 < CC; k0 += 32) {
            bf16x8 bfr[3];
            #pragma unroll
            for (int ni = 0; ni < 3; ++ni)
                bfr[ni] = cvt8(W + (size_t)(obase + ni * 16 + l16) * CC + k0 + quad * 8);
            #pragma unroll
            for (int mi = 0; mi < 4; ++mi) {
                bf16x8 afr = *(const bf16x8*)&xT[mi * 16 + l16][k0 + quad * 8];
                #pragma unroll
                for (int ni = 0; ni < 3; ++ni)
                    acc[mi][ni] = MFMA16(afr, bfr[ni], acc[mi][ni]);
            }
        }

        #pragma unroll
        for (int mi = 0; mi < 4; ++mi)
            #pragma unroll
            for (int ni = 0; ni < 3; ++ni) {
                const int ol  = obase + ni * 16 + l16;
                const int tl0 = mi * 16 + quad * 4;
                U2 lo2, hi2;
                lo2.h[0] = (bf16_t)acc[mi][ni][0]; lo2.h[1] = (bf16_t)acc[mi][ni][1];
                hi2.h[0] = (bf16_t)acc[mi][ni][2]; hi2.h[1] = (bf16_t)acc[mi][ni][3];
                uint2 pk; pk.x = lo2.u; pk.y = hi2.u;
                *(uint2*)(vm + ((size_t)b * CC + ol) * TT + t0 + tl0) = pk;
            }

        #pragma unroll
        for (int ni = 0; ni < 3; ++ni) {
            float s = 0.f;
            #pragma unroll
            for (int mi = 0; mi < 4; ++mi)
                #pragma unroll
                for (int r = 0; r < 4; ++r) s += acc[mi][ni][r];
            s += __shfl_xor(s, 16, 64);
            s += __shfl_xor(s, 32, 64);
            if (quad == 0)
                atomicAdd(&vrs[b * CC + obase + ni * 16 + l16], s);
        }
    }
}

// ---------------------------------------------------------------------------
// K2: fused attention. Grid 256 = 8 b (XCD-pinned) x 16 q-tiles x 2 t-halves.
// 512 thr / 8 waves = 4 q-groups (qg, 16 q each) x 2 t-slices (ts, 32 t of
// each 64-t tile). launch_bounds (512,1): min-waves=1 -> VGPR cap 512, the
// allocator lands at ~256 like round 3 (NO SPILL; round 5's (512,2) forced
// 128 VGPR -> 785 MB scratch traffic = whole kernel time). At 256 VGPR the
// 8-wave block is fully resident (2 waves/SIMD).
// Per-wave pipeline identical to round 3. LDS 96K: Ks[64][384] | Vs[384][64],
// 2 staging barriers/tile. Epilogue merges ts pairs in LDS, writes per-th
// U partials (nt) + l/l2 partials; stats_kernel merges th halves.
// ---------------------------------------------------------------------------
__global__ __launch_bounds__(512, 1) void fused_attn(
    const bf16_t* __restrict__ qT,
    const bf16_t* __restrict__ kT,
    const bf16_t* __restrict__ vm,
    const float*  __restrict__ head_w,
    float* __restrict__ Up,      // [2][8][6][1024][64]
    float* __restrict__ lp,      // [2][48][1024]
    float* __restrict__ l2p)     // [2][48][1024]
{
    const int L  = blockIdx.x;
    const int b  = L & 7;              // XCD-pinned
    const int rr = L >> 3;
    const int qt = rr & 15;            // 0..15 (64-q tile)
    const int th = rr >> 4;            // 0..1  (512-t half)

    const int tid = threadIdx.x, lane = tid & 63, wid = tid >> 6;
    const int quad = lane >> 4, l16 = lane & 15;
    const int qg = wid & 3, ts = wid >> 2;

    __shared__ __align__(16) bf16_t sm[49152];   // 96 KB: Ks[64][384] | Vs[384][64]
    bf16_t* Ks = sm;
    __shared__ float Lh[384], L2h[384];          // [qg][g][l16] merge buffers

    // mix coefficients -> SGPRs
    float mixc[36];
    #pragma unroll
    for (int j = 0; j < 36; ++j) {
        const float v = 0.125f * head_w[j];
        mixc[j] = __uint_as_float(__builtin_amdgcn_readfirstlane(__float_as_uint(v)));
    }

    // persistent Q fragments: rows q = qt*64 + qg*16 + l16
    bf16x8 qf[6][2];
    {
        const bf16_t* qp = qT + ((size_t)b * TT + qt * 64 + qg * 16 + l16) * CC + quad * 8;
        #pragma unroll
        for (int h = 0; h < 6; ++h)
            #pragma unroll
            for (int k2 = 0; k2 < 2; ++k2)
                qf[h][k2] = *(const bf16x8*)(qp + h * 64 + k2 * 32);
    }

    // staging: pre-swizzled global src, linear LDS dst. 3072 16B-chunks each,
    // 512 threads -> 6 chunks/thread.
    int koff[6], voff[6];
    #pragma unroll
    for (int i = 0; i < 6; ++i) {
        const int f = i * 512 + tid;
        const int krow = f / 48, kc = f - krow * 48;
        koff[i] = krow * CC + ((kc & 56) | ((kc ^ krow) & 7)) * 8;
        const int vrow = f >> 3, vc = f & 7;
        voff[i] = vrow * TT + ((vc ^ (vrow & 7)) * 8);
    }
    const bf16_t* kTb = kT + ((size_t)b * TT + th * 512) * CC;
    const bf16_t* vmb = vm + (size_t)b * CC * TT + th * 512;
    char* KsB = (char*)sm;
    char* VsB = (char*)sm + 49152;     // elem offset 24576
    const int ldst = tid * 16;

    // prologue: stage K tile 0
    #pragma unroll
    for (int i = 0; i < 6; ++i)
        gload_lds16(kTb + koff[i], KsB + i * 8192 + ldst);

    f32x4 U[6][4];
    const f32x4 zero = {0.f, 0.f, 0.f, 0.f};
    #pragma unroll
    for (int h = 0; h < 6; ++h)
        #pragma unroll
        for (int d = 0; d < 4; ++d) U[h][d] = zero;
    float lacc[6]  = {0.f, 0.f, 0.f, 0.f, 0.f, 0.f};
    float l2acc[6] = {0.f, 0.f, 0.f, 0.f, 0.f, 0.f};

    const int  s3    = l16 & 7;
    const int  rbase = ts * 32;
    const int  addrA = ((quad & 1) * 32 + l16) * 4;
    const int  addrB = addrA + 64;
    const bool qlo   = (quad < 2);

    __syncthreads();   // K tile 0 staged

    for (int tt = 0; tt < 8; ++tt) {
        // ---- issue V(t) (prev PV reads of Vs completed at prior B2)
        #pragma unroll
        for (int i = 0; i < 6; ++i)
            gload_lds16(vmb + tt * 64 + voff[i], VsB + i * 8192 + ldst);

        // ---- per-head scores: lane (q = l16, t = rbase + blk*16 + quad*4 + r)
        f32x4 S[6][2];
        #pragma unroll
        for (int h = 0; h < 6; ++h) {
            #pragma unroll
            for (int blk = 0; blk < 2; ++blk) {
                const bf16_t* Ar = Ks + (size_t)(rbase + blk * 16 + l16) * CC + h * 64;
                bf16x8 a0 = *(const bf16x8*)(Ar + ((quad ^ s3) * 8));
                bf16x8 a1 = *(const bf16x8*)(Ar + (((4 + quad) ^ s3) * 8));
                f32x4 s = MFMA16(a0, qf[h][0], zero);
                S[h][blk] = MFMA16(a1, qf[h][1], s);
            }
        }

        // ---- mix + exp + l/l2 + intra-wave transpose -> PV A-frags
        bf16x8 pa[6];
        #pragma unroll
        for (int g = 0; g < 6; ++g) {
            unsigned int uu[2][2];
            #pragma unroll
            for (int blk = 0; blk < 2; ++blk) {
                f32x4 m = mixc[g * 6] * S[0][blk];
                #pragma unroll
                for (int h2 = 1; h2 < 6; ++h2) m += mixc[g * 6 + h2] * S[h2][blk];
                f32x4 pv;
                #pragma unroll
                for (int r = 0; r < 4; ++r) pv[r] = __expf(fminf(m[r], 60.0f));
                lacc[g]  += pv[0] + pv[1] + pv[2] + pv[3];
                l2acc[g] += pv[0] * pv[0] + pv[1] * pv[1] + pv[2] * pv[2] + pv[3] * pv[3];
                U2 lo, hi;
                lo.h[0] = (bf16_t)pv[0]; lo.h[1] = (bf16_t)pv[1];
                hi.h[0] = (bf16_t)pv[2]; hi.h[1] = (bf16_t)pv[3];
                uu[blk][0] = lo.u; uu[blk][1] = hi.u;
            }
            int x0 = __builtin_amdgcn_ds_bpermute(addrA, (int)uu[0][0]);
            int y0 = __builtin_amdgcn_ds_bpermute(addrA, (int)uu[1][0]);
            int x1 = __builtin_amdgcn_ds_bpermute(addrA, (int)uu[0][1]);
            int y1 = __builtin_amdgcn_ds_bpermute(addrA, (int)uu[1][1]);
            int x2 = __builtin_amdgcn_ds_bpermute(addrB, (int)uu[0][0]);
            int y2 = __builtin_amdgcn_ds_bpermute(addrB, (int)uu[1][0]);
            int x3 = __builtin_amdgcn_ds_bpermute(addrB, (int)uu[0][1]);
            int y3 = __builtin_amdgcn_ds_bpermute(addrB, (int)uu[1][1]);
            I4B c;
            c.i = (i32x4){qlo ? x0 : y0, qlo ? x1 : y1, qlo ? x2 : y2, qlo ? x3 : y3};
            pa[g] = c.v;
        }

        __syncthreads();   // B1: Ks reads done; V(t) drained

        // ---- issue K(t+1) (hidden under PV)
        if (tt < 7) {
            #pragma unroll
            for (int i = 0; i < 6; ++i)
                gload_lds16(kTb + (size_t)(tt + 1) * 64 * CC + koff[i], KsB + i * 8192 + ldst);
        }

        // ---- PV: U[q][d] += P[q][t] * V[d][t] over wave's 32-t slice
        const bf16_t* Vb = sm + 24576;
        #pragma unroll
        for (int h = 0; h < 6; ++h) {
            #pragma unroll
            for (int n2 = 0; n2 < 4; ++n2) {
                bf16x8 bv = *(const bf16x8*)(Vb + (size_t)(h * 64 + n2 * 16 + l16) * 64
                                             + (((ts * 4 + quad) ^ s3) * 8));
                U[h][n2] = MFMA16(pa[h], bv, U[h][n2]);
            }
        }

        __syncthreads();   // B2: K(t+1) drained; Vs reads done
    }

    // ---- epilogue: merge the two ts waves per qg in LDS
    float* MB = (float*)sm;            // [4qg*6h*16q][64d] = 24576 floats (exact)

    float lrow[6], l2row[6];
    #pragma unroll
    for (int g = 0; g < 6; ++g) {
        float l = lacc[g], l2 = l2acc[g];
        l  += __shfl_xor(l, 16, 64);  l  += __shfl_xor(l, 32, 64);
        l2 += __shfl_xor(l2, 16, 64); l2 += __shfl_xor(l2, 32, 64);
        lrow[g] = l; l2row[g] = l2;
    }

    if (ts == 1) {
        #pragma unroll
        for (int h = 0; h < 6; ++h)
            #pragma unroll
            for (int n2 = 0; n2 < 4; ++n2)
                #pragma unroll
                for (int r = 0; r < 4; ++r)
                    MB[(size_t)((qg * 6 + h) * 16 + quad * 4 + r) * 64 + n2 * 16 + l16] = U[h][n2][r];
        if (quad == 0) {
            #pragma unroll
            for (int g = 0; g < 6; ++g) {
                Lh [(qg * 6 + g) * 16 + l16] = lrow[g];
                L2h[(qg * 6 + g) * 16 + l16] = l2row[g];
            }
        }
    }
    __syncthreads();

    if (ts == 0) {
        // per-th l/l2 partials
        if (quad == 0) {
            #pragma unroll
            for (int g = 0; g < 6; ++g) {
                const size_t o = ((size_t)th * 48 + b * 6 + g) * TT + qt * 64 + qg * 16 + l16;
                lp[o]  = lrow[g]  + Lh [(qg * 6 + g) * 16 + l16];
                l2p[o] = l2row[g] + L2h[(qg * 6 + g) * 16 + l16];
            }
        }
        // merged (over ts) U partial -> Up[th], nontemporal
        #pragma unroll
        for (int h = 0; h < 6; ++h) {
            float* Ub = Up + ((((size_t)th * 8 + b) * 6 + h) * TT + qt * 64 + qg * 16) * 64;
            #pragma unroll
            for (int n2 = 0; n2 < 4; ++n2)
                #pragma unroll
                for (int r = 0; r < 4; ++r) {
                    const float u = U[h][n2][r]
                        + MB[(size_t)((qg * 6 + h) * 16 + quad * 4 + r) * 64 + n2 * 16 + l16];
                    __builtin_nontemporal_store(u,
                        Ub + (size_t)(quad * 4 + r) * 64 + n2 * 16 + l16);
                }
        }
    }
}

// ---------------------------------------------------------------------------
// K2b: merge 2 t-half partials: linv[bg][q] = 1/sum(l), sq[bg] = sum_q l2/l^2
// ---------------------------------------------------------------------------
__global__ __launch_bounds__(256) void stats_kernel(
    const float* __restrict__ lp, const float* __restrict__ l2p,
    float* __restrict__ linv, float* __restrict__ sq)
{
    const int bg = blockIdx.x, tid = threadIdx.x;
    float c = 0.f;
    for (int q = tid; q < TT; q += 256) {
        const float l  = lp [(size_t)bg * TT + q] + lp [(size_t)(48 + bg) * TT + q];
        const float l2 = l2p[(size_t)bg * TT + q] + l2p[(size_t)(48 + bg) * TT + q];
        const float inv = 1.0f / l;
        linv[bg * TT + q] = inv;
        c += l2 * inv * inv;
    }
    #pragma unroll
    for (int off = 1; off < 64; off <<= 1) c += __shfl_xor(c, off, 64);
    __shared__ float red[4];
    if ((tid & 63) == 0) red[tid >> 6] = c;
    __syncthreads();
    if (tid == 0) sq[bg] = red[0] + red[1] + red[2] + red[3];
}

// ---------------------------------------------------------------------------
// K3: projection + fused InstanceNorm affine + bias + transpose.
// Grid (64,8): 16-t tiles -> 512 blocks = 2 blocks/CU (8 waves/CU).
//   off = t'*384 + c'; h = off>>16, q = (off>>6)&1023, d = off&63.
//   Z[t'][c'] = Ac[h]*((U0+U1)[off]) * linv[h*1024+q] + Cc[h]*vrs[b][h*64+d]
// ---------------------------------------------------------------------------
__global__ __launch_bounds__(256) void proj_kernel(
    const float* __restrict__ Up,
    const float* __restrict__ linv,
    const float* __restrict__ vrs,
    const float* __restrict__ sumsq,
    const float* __restrict__ gamma,
    const float* __restrict__ beta,
    const float* __restrict__ projW,
    const float* __restrict__ projb,
    float* __restrict__ out)
{
    const int ts = blockIdx.x;
    const int b  = blockIdx.y;
    const int t0 = ts * 16;
    const int tid = threadIdx.x, lane = tid & 63, wid = tid >> 6;
    const int quad = lane >> 4, l16 = lane & 15;

    __shared__ float Ac[6], Cc[6], pb[CC];
    if (tid < 6) {
        const float ss  = sumsq[b * NHH + tid];
        const float var = fmaxf(ss - 1.0f, 0.0f) * (1.0f / 1048576.0f);
        const float a   = gamma[tid] * rsqrtf(var + 1e-5f);
        Ac[tid] = a;
        Cc[tid] = beta[tid] - a * (1.0f / 1024.0f);
    }
    for (int i = tid; i < CC; i += 256) pb[i] = projb[i];
    __syncthreads();

    f32x4 acc[6];
    const f32x4 zero = {0.f, 0.f, 0.f, 0.f};
    #pragma unroll
    for (int mi = 0; mi < 6; ++mi) acc[mi] = zero;

    constexpr size_t PST = (size_t)BB * NHH * TT * 64;
    const float* U0 = Up + (size_t)b * (NHH * TT * 64);
    const float* U1 = U0 + PST;
    for (int k0 = 0; k0 < CC; k0 += 32) {
        const int tl = t0 + l16;
        const int baseoff = tl * CC + k0 + quad * 8;
        const int hh = baseoff >> 16;                 // constant over j (8-aligned)
        const int d0 = baseoff & 63;                  // d of j=0; d0+7 <= 63
        const float li = linv[b * 6144 + (baseoff >> 6)];
        const float Al = Ac[hh] * li;
        const float Cb = Cc[hh];
        f32x4 u0 = __builtin_nontemporal_load((const f32x4*)(U0 + baseoff))
                 + __builtin_nontemporal_load((const f32x4*)(U1 + baseoff));
        f32x4 u1 = __builtin_nontemporal_load((const f32x4*)(U0 + baseoff + 4))
                 + __builtin_nontemporal_load((const f32x4*)(U1 + baseoff + 4));
        U8 z;
        #pragma unroll
        for (int j = 0; j < 8; ++j) {
            const float uv = (j < 4) ? u0[j] : u1[j - 4];
            z.h[j] = (bf16_t)(Al * uv + Cb * vrs[b * CC + hh * 64 + d0 + j]);
        }
        bf16x8 bfr = *(const bf16x8*)&z;
        #pragma unroll
        for (int mi = 0; mi < 6; ++mi) {
            const int o = wid * 96 + mi * 16 + l16;
            bf16x8 afr = cvt8(projW + (size_t)o * CC + k0 + quad * 8);
            acc[mi] = MFMA16(afr, bfr, acc[mi]);
        }
    }

    #pragma unroll
    for (int mi = 0; mi < 6; ++mi)
        #pragma unroll
        for (int r = 0; r < 4; ++r) {
            const int o  = wid * 96 + mi * 16 + quad * 4 + r;
            const int tl = t0 + l16;
            out[((size_t)b * CC + o) * TT + tl] = acc[mi][r] + pb[o];
        }
}

// ---------------------------------------------------------------------------
extern "C" void kernel_launch(void* const* d_in, const int* in_sizes, int n_in,
                              void* d_out, int out_size, void* d_ws, size_t ws_size,
                              hipStream_t stream)
{
    float* outp = (float*)d_out;
    char* ws = (char*)d_ws;

    size_t off = 0;
    auto alloc = [&](size_t bytes) {
        void* p = ws + off;
        off += (bytes + 255) & ~(size_t)255;
        return p;
    };

    const size_t szT = (size_t)BB * TT * CC * sizeof(bf16_t);   // 6.29 MB

    bf16_t* qTb = (bf16_t*)alloc(szT);
    bf16_t* kTb = (bf16_t*)alloc(szT);
    bf16_t* vmb = (bf16_t*)alloc(szT);
    float*  Uh  = (float*)alloc((size_t)2 * BB * NHH * TT * 64 * sizeof(float)); // 25.2 MB
    float*  lpb = (float*)alloc((size_t)2 * 48 * TT * sizeof(float));
    float*  l2b = (float*)alloc((size_t)2 * 48 * TT * sizeof(float));
    float*  lv  = (float*)alloc((size_t)48 * TT * sizeof(float));
    float*  vr  = (float*)alloc((size_t)BB * CC * sizeof(float));
    float*  sq  = (float*)alloc(48 * sizeof(float));

    hipMemsetAsync(vr, 0, (size_t)BB * CC * sizeof(float), stream);
    qkv_kernel<<<dim3(16, 6, 8), 256, 0, stream>>>(
        (const float*)d_in[0], (const float*)d_in[1], (const float*)d_in[2],
        (const float*)d_in[3], qTb, kTb, vmb, vr);
    fused_attn<<<256, 512, 0, stream>>>(
        qTb, kTb, vmb, (const float*)d_in[4], Uh, lpb, l2b);
    stats_kernel<<<48, 256, 0, stream>>>(lpb, l2b, lv, sq);
    proj_kernel<<<dim3(64, 8), 256, 0, stream>>>(
        Uh, lv, vr, sq, (const float*)d_in[5], (const float*)d_in[6],
        (const float*)d_in[7], (const float*)d_in[8], outp);
}

// Round 8
// 259.079 us; speedup vs baseline: 1.3637x; 1.3637x over previous
//
#include <hip/hip_runtime.h>
#include <hip/hip_bf16.h>
#include <cstdint>

typedef __bf16 bf16_t;
typedef __bf16 bf16x8 __attribute__((ext_vector_type(8)));
typedef float  f32x4  __attribute__((ext_vector_type(4)));
typedef int    i32x4  __attribute__((ext_vector_type(4)));

#define MFMA16(a, b, c) __builtin_amdgcn_mfma_f32_16x16x32_bf16((a), (b), (c), 0, 0, 0)

constexpr int BB = 8, CC = 384, NHH = 6, TT = 1024;

union U8 { uint4 u; bf16_t h[8]; };
union U2 { unsigned int u; bf16_t h[2]; };
union I4B { i32x4 i; bf16x8 v; };

static __device__ __forceinline__ void gload_lds16(const void* g, void* l) {
    __builtin_amdgcn_global_load_lds((const __attribute__((address_space(1))) void*)g,
                                     (__attribute__((address_space(3))) void*)l, 16, 0, 0);
}

// load 8 consecutive fp32 -> bf16x8
static __device__ __forceinline__ bf16x8 cvt8(const float* p) {
    f32x4 a = *(const f32x4*)p, b = *(const f32x4*)(p + 4);
    U8 o;
    #pragma unroll
    for (int j = 0; j < 4; ++j) { o.h[j] = (bf16_t)a[j]; o.h[4 + j] = (bf16_t)b[j]; }
    return *(bf16x8*)&o;
}

// ---------------------------------------------------------------------------
// K1: QKV projection from fp32 inputs (cast fused). vrow fused via atomics.
// Grid dim3(16,6,8): tt=x, og=y, b=z so the 6 og-blocks of one (b,tt) have
// linear ids differing by 16 -> same XCD: x-tile fetched from HBM once.
// ---------------------------------------------------------------------------
__global__ __launch_bounds__(256) void qkv_kernel(
    const float* __restrict__ x,
    const float* __restrict__ Wq,
    const float* __restrict__ Wk,
    const float* __restrict__ Wv,
    bf16_t* __restrict__ qT,
    bf16_t* __restrict__ kT,
    bf16_t* __restrict__ vm,
    float*  __restrict__ vrs)
{
    const int tt = blockIdx.x;
    const int og = blockIdx.y;        // 0,1:q  2,3:k  4,5:v  (og&1 = o-half)
    const int b  = blockIdx.z;
    const int t0 = tt * 64;
    const int tid  = threadIdx.x;
    const int lane = tid & 63;
    const int wid  = tid >> 6;
    const int quad = lane >> 4;
    const int l16  = lane & 15;

    __shared__ __align__(16) bf16_t xT[64][CC + 8];

    {
        const float* xb = x + (size_t)b * CC * TT;
        const int tq = tid & 7;
        const int cp = tid >> 3;
        #pragma unroll
        for (int pass = 0; pass < 6; ++pass) {
            const int c = (pass * 32 + cp) * 2;
            const float* r0 = xb + (size_t)c * TT + t0 + tq * 8;
            const float* r1 = r0 + TT;
            f32x4 a0 = *(const f32x4*)r0, a1 = *(const f32x4*)(r0 + 4);
            f32x4 b0 = *(const f32x4*)r1, b1 = *(const f32x4*)(r1 + 4);
            #pragma unroll
            for (int j = 0; j < 8; ++j) {
                U2 p;
                p.h[0] = (bf16_t)((j < 4) ? a0[j] : a1[j - 4]);
                p.h[1] = (bf16_t)((j < 4) ? b0[j] : b1[j - 4]);
                *(unsigned int*)&xT[tq * 8 + j][c] = p.u;
            }
        }
    }
    __syncthreads();

    const float* W = (og < 2) ? Wq : (og < 4) ? Wk : Wv;
    const int obase = (og & 1) * 192 + wid * 48;

    if (og < 4) {
        f32x4 acc[3][4];
        const f32x4 zero = {0.f, 0.f, 0.f, 0.f};
        #pragma unroll
        for (int mi = 0; mi < 3; ++mi)
            #pragma unroll
            for (int ni = 0; ni < 4; ++ni) acc[mi][ni] = zero;

        for (int k0 = 0; k0 < CC; k0 += 32) {
            bf16x8 afr[3];
            #pragma unroll
            for (int mi = 0; mi < 3; ++mi)
                afr[mi] = cvt8(W + (size_t)(obase + mi * 16 + l16) * CC + k0 + quad * 8);
            #pragma unroll
            for (int ni = 0; ni < 4; ++ni) {
                bf16x8 bfr = *(const bf16x8*)&xT[ni * 16 + l16][k0 + quad * 8];
                #pragma unroll
                for (int mi = 0; mi < 3; ++mi)
                    acc[mi][ni] = MFMA16(afr[mi], bfr, acc[mi][ni]);
            }
        }

        bf16_t* dst = (og < 2) ? qT : kT;
        #pragma unroll
        for (int mi = 0; mi < 3; ++mi)
            #pragma unroll
            for (int ni = 0; ni < 4; ++ni) {
                const int o0 = obase + mi * 16 + quad * 4;
                const int tl = t0 + ni * 16 + l16;
                U2 lo2, hi2;
                lo2.h[0] = (bf16_t)acc[mi][ni][0]; lo2.h[1] = (bf16_t)acc[mi][ni][1];
                hi2.h[0] = (bf16_t)acc[mi][ni][2]; hi2.h[1] = (bf16_t)acc[mi][ni][3];
                uint2 pk; pk.x = lo2.u; pk.y = hi2.u;
                *(uint2*)(dst + ((size_t)b * TT + tl) * CC + o0) = pk;
            }
    } else {
        f32x4 acc[4][3];
        const f32x4 zero = {0.f, 0.f, 0.f, 0.f};
        #pragma unroll
        for (int mi = 0; mi < 4; ++mi)
            #pragma unroll
            for (int ni = 0; ni < 3; ++ni) acc[mi][ni] = zero;

        for (int k0 = 0; k0 < CC; k0 += 32) {
            bf16x8 bfr[3];
            #pragma unroll
            for (int ni = 0; ni < 3; ++ni)
                bfr[ni] = cvt8(W + (size_t)(obase + ni * 16 + l16) * CC + k0 + quad * 8);
            #pragma unroll
            for (int mi = 0; mi < 4; ++mi) {
                bf16x8 afr = *(const bf16x8*)&xT[mi * 16 + l16][k0 + quad * 8];
                #pragma unroll
                for (int ni = 0; ni < 3; ++ni)
                    acc[mi][ni] = MFMA16(afr, bfr[ni], acc[mi][ni]);
            }
        }

        #pragma unroll
        for (int mi = 0; mi < 4; ++mi)
            #pragma unroll
            for (int ni = 0; ni < 3; ++ni) {
                const int ol  = obase + ni * 16 + l16;
                const int tl0 = mi * 16 + quad * 4;
                U2 lo2, hi2;
                lo2.h[0] = (bf16_t)acc[mi][ni][0]; lo2.h[1] = (bf16_t)acc[mi][ni][1];
                hi2.h[0] = (bf16_t)acc[mi][ni][2]; hi2.h[1] = (bf16_t)acc[mi][ni][3];
                uint2 pk; pk.x = lo2.u; pk.y = hi2.u;
                *(uint2*)(vm + ((size_t)b * CC + ol) * TT + t0 + tl0) = pk;
            }

        #pragma unroll
        for (int ni = 0; ni < 3; ++ni) {
            float s = 0.f;
            #pragma unroll
            for (int mi = 0; mi < 4; ++mi)
                #pragma unroll
                for (int r = 0; r < 4; ++r) s += acc[mi][ni][r];
            s += __shfl_xor(s, 16, 64);
            s += __shfl_xor(s, 32, 64);
            if (quad == 0)
                atomicAdd(&vrs[b * CC + obase + ni * 16 + l16], s);
        }
    }
}

// ---------------------------------------------------------------------------
// K2: fused attention. Grid 512 = 8 b (XCD-pinned) x 16 q-tiles(64q) x 4
// t-quarters(256t). 256 thr / 4 waves; wave = q-group qg=wid (16 q, ALL 6
// heads, full 32-t tile -> NO intra-block merge). 256-thr blocks compile to
// 256 VGPR with no spill (round 3 proven; 512-thr blocks cap at 128 VGPR ->
// 780 MB scratch = rounds 5/6 pathology). LDS 48 KB (Ks[32][384]|Vs[384][32])
// -> 2 blocks/CU (VGPR-limited), 8 waves/CU. 2 staging barriers per 32-t
// tile; V(t) issued at tile top, K(t+1) after B1. Epilogue: direct per-wave
// U[6][4] nt-store to Up[tq] + quad-reduced l/l2 partials (no LDS, no bar).
// ---------------------------------------------------------------------------
__global__ __launch_bounds__(256, 1) void fused_attn(
    const bf16_t* __restrict__ qT,
    const bf16_t* __restrict__ kT,
    const bf16_t* __restrict__ vm,
    const float*  __restrict__ head_w,
    float* __restrict__ Up,      // [4][8][6][1024][64]
    float* __restrict__ lp,      // [4][48][1024]
    float* __restrict__ l2p)     // [4][48][1024]
{
    const int L  = blockIdx.x;
    const int b  = L & 7;              // XCD-pinned
    const int rr = L >> 3;
    const int qt = rr & 15;            // 0..15 (64-q tile)
    const int tq = rr >> 4;            // 0..3  (256-t quarter)
    const int T0 = tq * 256;

    const int tid = threadIdx.x, lane = tid & 63, wid = tid >> 6;
    const int quad = lane >> 4, l16 = lane & 15;

    __shared__ __align__(16) bf16_t sm[24576];   // 48 KB: Ks[32][384] | Vs[384][32]
    bf16_t* Ks = sm;

    // mix coefficients -> SGPRs
    float mixc[36];
    #pragma unroll
    for (int j = 0; j < 36; ++j) {
        const float v = 0.125f * head_w[j];
        mixc[j] = __uint_as_float(__builtin_amdgcn_readfirstlane(__float_as_uint(v)));
    }

    // persistent Q fragments: rows q = qt*64 + wid*16 + l16
    bf16x8 qf[6][2];
    {
        const bf16_t* qp = qT + ((size_t)b * TT + qt * 64 + wid * 16 + l16) * CC + quad * 8;
        #pragma unroll
        for (int h = 0; h < 6; ++h)
            #pragma unroll
            for (int k2 = 0; k2 < 2; ++k2)
                qf[h][k2] = *(const bf16x8*)(qp + h * 64 + k2 * 32);
    }

    // staging: pre-swizzled global src, linear LDS dst. 1536 16B-chunks each
    // (24 KB), 256 threads -> 6 chunks/thread.
    int koff[6], voff[6];
    #pragma unroll
    for (int i = 0; i < 6; ++i) {
        const int f = i * 256 + tid;
        const int krow = f / 48, kc = f - krow * 48;           // Ks: 32 rows x 48 chunks
        koff[i] = krow * CC + ((kc & 56) | ((kc ^ krow) & 7)) * 8;
        const int vrow = f >> 2, vc = f & 3;                   // Vs: 384 rows x 4 chunks
        voff[i] = vrow * TT + ((vc ^ ((vrow >> 1) & 3)) * 8);
    }
    const bf16_t* kTb = kT + ((size_t)b * TT + T0) * CC;
    const bf16_t* vmb = vm + (size_t)b * CC * TT + T0;
    char* KsB = (char*)sm;
    char* VsB = (char*)sm + 24576;     // elem offset 12288
    const int ldst = tid * 16;

    // prologue: stage K tile 0
    #pragma unroll
    for (int i = 0; i < 6; ++i)
        gload_lds16(kTb + koff[i], KsB + i * 4096 + ldst);

    f32x4 U[6][4];
    const f32x4 zero = {0.f, 0.f, 0.f, 0.f};
    #pragma unroll
    for (int h = 0; h < 6; ++h)
        #pragma unroll
        for (int d = 0; d < 4; ++d) U[h][d] = zero;
    float lacc[6]  = {0.f, 0.f, 0.f, 0.f, 0.f, 0.f};
    float l2acc[6] = {0.f, 0.f, 0.f, 0.f, 0.f, 0.f};

    const int  s3    = l16 & 7;
    const int  vswz  = (quad ^ ((l16 >> 1) & 3)) * 8;
    const int  addrA = ((quad & 1) * 32 + l16) * 4;
    const int  addrB = addrA + 64;
    const bool qlo   = (quad < 2);

    __syncthreads();   // K tile 0 staged

    for (int tt = 0; tt < 8; ++tt) {
        // ---- issue V(t) (Vs reads of tile t-1 completed at prior B2)
        #pragma unroll
        for (int i = 0; i < 6; ++i)
            gload_lds16(vmb + tt * 32 + voff[i], VsB + i * 4096 + ldst);

        // ---- per-head scores: lane (q = l16, t = blk*16 + quad*4 + r)
        f32x4 S[6][2];
        #pragma unroll
        for (int h = 0; h < 6; ++h) {
            #pragma unroll
            for (int blk = 0; blk < 2; ++blk) {
                const bf16_t* Ar = Ks + (size_t)(blk * 16 + l16) * CC + h * 64;
                bf16x8 a0 = *(const bf16x8*)(Ar + ((quad ^ s3) * 8));
                bf16x8 a1 = *(const bf16x8*)(Ar + (((4 + quad) ^ s3) * 8));
                f32x4 s = MFMA16(a0, qf[h][0], zero);
                S[h][blk] = MFMA16(a1, qf[h][1], s);
            }
        }

        // ---- mix + exp + l/l2 + intra-wave transpose -> PV A-frags
        bf16x8 pa[6];
        #pragma unroll
        for (int g = 0; g < 6; ++g) {
            unsigned int uu[2][2];
            #pragma unroll
            for (int blk = 0; blk < 2; ++blk) {
                f32x4 m = mixc[g * 6] * S[0][blk];
                #pragma unroll
                for (int h2 = 1; h2 < 6; ++h2) m += mixc[g * 6 + h2] * S[h2][blk];
                f32x4 pv;
                #pragma unroll
                for (int r = 0; r < 4; ++r) pv[r] = __expf(fminf(m[r], 60.0f));
                lacc[g]  += pv[0] + pv[1] + pv[2] + pv[3];
                l2acc[g] += pv[0] * pv[0] + pv[1] * pv[1] + pv[2] * pv[2] + pv[3] * pv[3];
                U2 lo, hi;
                lo.h[0] = (bf16_t)pv[0]; lo.h[1] = (bf16_t)pv[1];
                hi.h[0] = (bf16_t)pv[2]; hi.h[1] = (bf16_t)pv[3];
                uu[blk][0] = lo.u; uu[blk][1] = hi.u;
            }
            int x0 = __builtin_amdgcn_ds_bpermute(addrA, (int)uu[0][0]);
            int y0 = __builtin_amdgcn_ds_bpermute(addrA, (int)uu[1][0]);
            int x1 = __builtin_amdgcn_ds_bpermute(addrA, (int)uu[0][1]);
            int y1 = __builtin_amdgcn_ds_bpermute(addrA, (int)uu[1][1]);
            int x2 = __builtin_amdgcn_ds_bpermute(addrB, (int)uu[0][0]);
            int y2 = __builtin_amdgcn_ds_bpermute(addrB, (int)uu[1][0]);
            int x3 = __builtin_amdgcn_ds_bpermute(addrB, (int)uu[0][1]);
            int y3 = __builtin_amdgcn_ds_bpermute(addrB, (int)uu[1][1]);
            I4B c;
            c.i = (i32x4){qlo ? x0 : y0, qlo ? x1 : y1, qlo ? x2 : y2, qlo ? x3 : y3};
            pa[g] = c.v;
        }

        __syncthreads();   // B1: Ks reads done; V(t) drained

        // ---- issue K(t+1) (hidden under PV)
        if (tt < 7) {
            #pragma unroll
            for (int i = 0; i < 6; ++i)
                gload_lds16(kTb + (size_t)(tt + 1) * 32 * CC + koff[i], KsB + i * 4096 + ldst);
        }

        // ---- PV: U[q][d] += P[q][t] * V[d][t] over the 32-t tile
        const bf16_t* Vb = sm + 12288;
        #pragma unroll
        for (int h = 0; h < 6; ++h) {
            #pragma unroll
            for (int n2 = 0; n2 < 4; ++n2) {
                bf16x8 bv = *(const bf16x8*)(Vb + (size_t)(h * 64 + n2 * 16 + l16) * 32 + vswz);
                U[h][n2] = MFMA16(pa[h], bv, U[h][n2]);
            }
        }

        __syncthreads();   // B2: K(t+1) drained; Vs reads done
    }

    // ---- epilogue: direct per-wave outputs (no intra-block merge needed)
    #pragma unroll
    for (int g = 0; g < 6; ++g) {
        float l = lacc[g], l2 = l2acc[g];
        l  += __shfl_xor(l, 16, 64);  l  += __shfl_xor(l, 32, 64);
        l2 += __shfl_xor(l2, 16, 64); l2 += __shfl_xor(l2, 32, 64);
        if (quad == 0) {
            const size_t o = ((size_t)tq * 48 + b * 6 + g) * TT + qt * 64 + wid * 16 + l16;
            lp[o] = l; l2p[o] = l2;
        }
    }

    #pragma unroll
    for (int h = 0; h < 6; ++h) {
        float* Ub = Up + ((((size_t)tq * 8 + b) * 6 + h) * TT + qt * 64 + wid * 16) * 64;
        #pragma unroll
        for (int n2 = 0; n2 < 4; ++n2)
            #pragma unroll
            for (int r = 0; r < 4; ++r)
                __builtin_nontemporal_store(U[h][n2][r],
                    Ub + (size_t)(quad * 4 + r) * 64 + n2 * 16 + l16);
    }
}

// ---------------------------------------------------------------------------
// K2b: merge 4 t-quarter partials: linv[bg][q] = 1/sum(l), sq[bg] = sum l2/l^2
// ---------------------------------------------------------------------------
__global__ __launch_bounds__(256) void stats_kernel(
    const float* __restrict__ lp, const float* __restrict__ l2p,
    float* __restrict__ linv, float* __restrict__ sq)
{
    const int bg = blockIdx.x, tid = threadIdx.x;
    float c = 0.f;
    for (int q = tid; q < TT; q += 256) {
        const float l  = lp [(size_t)bg * TT + q] + lp [(size_t)(48 + bg) * TT + q]
                       + lp [(size_t)(96 + bg) * TT + q] + lp [(size_t)(144 + bg) * TT + q];
        const float l2 = l2p[(size_t)bg * TT + q] + l2p[(size_t)(48 + bg) * TT + q]
                       + l2p[(size_t)(96 + bg) * TT + q] + l2p[(size_t)(144 + bg) * TT + q];
        const float inv = 1.0f / l;
        linv[bg * TT + q] = inv;
        c += l2 * inv * inv;
    }
    #pragma unroll
    for (int off = 1; off < 64; off <<= 1) c += __shfl_xor(c, off, 64);
    __shared__ float red[4];
    if ((tid & 63) == 0) red[tid >> 6] = c;
    __syncthreads();
    if (tid == 0) sq[bg] = red[0] + red[1] + red[2] + red[3];
}

// ---------------------------------------------------------------------------
// K3: projection + fused InstanceNorm affine + bias + transpose.
// Grid (64,8): 16-t tiles -> 512 blocks = 2 blocks/CU.
//   off = t'*384 + c'; h = off>>16, q = (off>>6)&1023, d = off&63.
//   Z[t'][c'] = Ac[h]*(sum_p Up[p][off]) * linv[h*1024+q] + Cc[h]*vrs[b][h*64+d]
// ---------------------------------------------------------------------------
__global__ __launch_bounds__(256) void proj_kernel(
    const float* __restrict__ Up,
    const float* __restrict__ linv,
    const float* __restrict__ vrs,
    const float* __restrict__ sumsq,
    const float* __restrict__ gamma,
    const float* __restrict__ beta,
    const float* __restrict__ projW,
    const float* __restrict__ projb,
    float* __restrict__ out)
{
    const int ts = blockIdx.x;
    const int b  = blockIdx.y;
    const int t0 = ts * 16;
    const int tid = threadIdx.x, lane = tid & 63, wid = tid >> 6;
    const int quad = lane >> 4, l16 = lane & 15;

    __shared__ float Ac[6], Cc[6], pb[CC];
    if (tid < 6) {
        const float ss  = sumsq[b * NHH + tid];
        const float var = fmaxf(ss - 1.0f, 0.0f) * (1.0f / 1048576.0f);
        const float a   = gamma[tid] * rsqrtf(var + 1e-5f);
        Ac[tid] = a;
        Cc[tid] = beta[tid] - a * (1.0f / 1024.0f);
    }
    for (int i = tid; i < CC; i += 256) pb[i] = projb[i];
    __syncthreads();

    f32x4 acc[6];
    const f32x4 zero = {0.f, 0.f, 0.f, 0.f};
    #pragma unroll
    for (int mi = 0; mi < 6; ++mi) acc[mi] = zero;

    constexpr size_t PST = (size_t)BB * NHH * TT * 64;
    const float* Ub = Up + (size_t)b * (NHH * TT * 64);
    for (int k0 = 0; k0 < CC; k0 += 32) {
        const int tl = t0 + l16;
        const int baseoff = tl * CC + k0 + quad * 8;
        const int hh = baseoff >> 16;                 // constant over j (8-aligned)
        const int d0 = baseoff & 63;                  // d of j=0; d0+7 <= 63
        const float li = linv[b * 6144 + (baseoff >> 6)];
        const float Al = Ac[hh] * li;
        const float Cb = Cc[hh];
        f32x4 u0 = __builtin_nontemporal_load((const f32x4*)(Ub + baseoff))
                 + __builtin_nontemporal_load((const f32x4*)(Ub + PST + baseoff))
                 + __builtin_nontemporal_load((const f32x4*)(Ub + 2 * PST + baseoff))
                 + __builtin_nontemporal_load((const f32x4*)(Ub + 3 * PST + baseoff));
        f32x4 u1 = __builtin_nontemporal_load((const f32x4*)(Ub + baseoff + 4))
                 + __builtin_nontemporal_load((const f32x4*)(Ub + PST + baseoff + 4))
                 + __builtin_nontemporal_load((const f32x4*)(Ub + 2 * PST + baseoff + 4))
                 + __builtin_nontemporal_load((const f32x4*)(Ub + 3 * PST + baseoff + 4));
        U8 z;
        #pragma unroll
        for (int j = 0; j < 8; ++j) {
            const float uv = (j < 4) ? u0[j] : u1[j - 4];
            z.h[j] = (bf16_t)(Al * uv + Cb * vrs[b * CC + hh * 64 + d0 + j]);
        }
        bf16x8 bfr = *(const bf16x8*)&z;
        #pragma unroll
        for (int mi = 0; mi < 6; ++mi) {
            const int o = wid * 96 + mi * 16 + l16;
            bf16x8 afr = cvt8(projW + (size_t)o * CC + k0 + quad * 8);
            acc[mi] = MFMA16(afr, bfr, acc[mi]);
        }
    }

    #pragma unroll
    for (int mi = 0; mi < 6; ++mi)
        #pragma unroll
        for (int r = 0; r < 4; ++r) {
            const int o  = wid * 96 + mi * 16 + quad * 4 + r;
            const int tl = t0 + l16;
            out[((size_t)b * CC + o) * TT + tl] = acc[mi][r] + pb[o];
        }
}

// ---------------------------------------------------------------------------
extern "C" void kernel_launch(void* const* d_in, const int* in_sizes, int n_in,
                              void* d_out, int out_size, void* d_ws, size_t ws_size,
                              hipStream_t stream)
{
    float* outp = (float*)d_out;
    char* ws = (char*)d_ws;

    size_t off = 0;
    auto alloc = [&](size_t bytes) {
        void* p = ws + off;
        off += (bytes + 255) & ~(size_t)255;
        return p;
    };

    const size_t szT = (size_t)BB * TT * CC * sizeof(bf16_t);   // 6.29 MB

    bf16_t* qTb = (bf16_t*)alloc(szT);
    bf16_t* kTb = (bf16_t*)alloc(szT);
    bf16_t* vmb = (bf16_t*)alloc(szT);
    float*  Uh  = (float*)alloc((size_t)4 * BB * NHH * TT * 64 * sizeof(float)); // 50.3 MB
    float*  lpb = (float*)alloc((size_t)4 * 48 * TT * sizeof(float));
    float*  l2b = (float*)alloc((size_t)4 * 48 * TT * sizeof(float));
    float*  lv  = (float*)alloc((size_t)48 * TT * sizeof(float));
    float*  vr  = (float*)alloc((size_t)BB * CC * sizeof(float));
    float*  sq  = (float*)alloc(48 * sizeof(float));

    hipMemsetAsync(vr, 0, (size_t)BB * CC * sizeof(float), stream);
    qkv_kernel<<<dim3(16, 6, 8), 256, 0, stream>>>(
        (const float*)d_in[0], (const float*)d_in[1], (const float*)d_in[2],
        (const float*)d_in[3], qTb, kTb, vmb, vr);
    fused_attn<<<512, 256, 0, stream>>>(
        qTb, kTb, vmb, (const float*)d_in[4], Uh, lpb, l2b);
    stats_kernel<<<48, 256, 0, stream>>>(lpb, l2b, lv, sq);
    proj_kernel<<<dim3(64, 8), 256, 0, stream>>>(
        Uh, lv, vr, sq, (const float*)d_in[5], (const float*)d_in[6],
        (const float*)d_in[7], (const float*)d_in[8], outp);
}

// Round 9
// 210.369 us; speedup vs baseline: 1.6794x; 1.2315x over previous
//
#include <hip/hip_runtime.h>
#include <hip/hip_bf16.h>
#include <cstdint>

typedef __bf16 bf16_t;
typedef __bf16 bf16x8 __attribute__((ext_vector_type(8)));
typedef float  f32x4  __attribute__((ext_vector_type(4)));
typedef int    i32x4  __attribute__((ext_vector_type(4)));

#define MFMA16(a, b, c) __builtin_amdgcn_mfma_f32_16x16x32_bf16((a), (b), (c), 0, 0, 0)

constexpr int BB = 8, CC = 384, NHH = 6, TT = 1024;

union U8 { uint4 u; bf16_t h[8]; };
union U2 { unsigned int u; bf16_t h[2]; };
union I4B { i32x4 i; bf16x8 v; };

static __device__ __forceinline__ void gload_lds16(const void* g, void* l) {
    __builtin_amdgcn_global_load_lds((const __attribute__((address_space(1))) void*)g,
                                     (__attribute__((address_space(3))) void*)l, 16, 0, 0);
}

// ---------------------------------------------------------------------------
// K0: one-shot weight cast fp32 -> bf16 (Wq, Wk, Wv, projW). 147456 elems
// each = 72 blocks x 256 thr x 8. Removes per-k-step cvt8 from qkv/proj.
// ---------------------------------------------------------------------------
__global__ __launch_bounds__(256) void castw_kernel(
    const float* __restrict__ w0, const float* __restrict__ w1,
    const float* __restrict__ w2, const float* __restrict__ w3,
    bf16_t* __restrict__ d0, bf16_t* __restrict__ d1,
    bf16_t* __restrict__ d2, bf16_t* __restrict__ d3)
{
    const int wi = blockIdx.y;
    const float* s = (wi == 0) ? w0 : (wi == 1) ? w1 : (wi == 2) ? w2 : w3;
    bf16_t*      d = (wi == 0) ? d0 : (wi == 1) ? d1 : (wi == 2) ? d2 : d3;
    const int idx = (blockIdx.x * 256 + threadIdx.x) * 8;
    f32x4 a = *(const f32x4*)(s + idx);
    f32x4 b = *(const f32x4*)(s + idx + 4);
    U8 o;
    #pragma unroll
    for (int j = 0; j < 4; ++j) { o.h[j] = (bf16_t)a[j]; o.h[4 + j] = (bf16_t)b[j]; }
    *(uint4*)(d + idx) = o.u;
}

// ---------------------------------------------------------------------------
// K1: QKV projection (bf16 weights from castw; fp32 x cast during staging).
// vrow fused via atomics. Grid dim3(16,6,8): the 6 og-blocks of one (b,tt)
// share an XCD -> x-tile fetched from HBM once.
// ---------------------------------------------------------------------------
__global__ __launch_bounds__(256) void qkv_kernel(
    const float* __restrict__ x,
    const bf16_t* __restrict__ Wq,
    const bf16_t* __restrict__ Wk,
    const bf16_t* __restrict__ Wv,
    bf16_t* __restrict__ qT,
    bf16_t* __restrict__ kT,
    bf16_t* __restrict__ vm,
    float*  __restrict__ vrs)
{
    const int tt = blockIdx.x;
    const int og = blockIdx.y;        // 0,1:q  2,3:k  4,5:v  (og&1 = o-half)
    const int b  = blockIdx.z;
    const int t0 = tt * 64;
    const int tid  = threadIdx.x;
    const int lane = tid & 63;
    const int wid  = tid >> 6;
    const int quad = lane >> 4;
    const int l16  = lane & 15;

    __shared__ __align__(16) bf16_t xT[64][CC + 8];

    {
        const float* xb = x + (size_t)b * CC * TT;
        const int tq = tid & 7;
        const int cp = tid >> 3;
        #pragma unroll
        for (int pass = 0; pass < 6; ++pass) {
            const int c = (pass * 32 + cp) * 2;
            const float* r0 = xb + (size_t)c * TT + t0 + tq * 8;
            const float* r1 = r0 + TT;
            f32x4 a0 = *(const f32x4*)r0, a1 = *(const f32x4*)(r0 + 4);
            f32x4 b0 = *(const f32x4*)r1, b1 = *(const f32x4*)(r1 + 4);
            #pragma unroll
            for (int j = 0; j < 8; ++j) {
                U2 p;
                p.h[0] = (bf16_t)((j < 4) ? a0[j] : a1[j - 4]);
                p.h[1] = (bf16_t)((j < 4) ? b0[j] : b1[j - 4]);
                *(unsigned int*)&xT[tq * 8 + j][c] = p.u;
            }
        }
    }
    __syncthreads();

    const bf16_t* W = (og < 2) ? Wq : (og < 4) ? Wk : Wv;
    const int obase = (og & 1) * 192 + wid * 48;

    if (og < 4) {
        f32x4 acc[3][4];
        const f32x4 zero = {0.f, 0.f, 0.f, 0.f};
        #pragma unroll
        for (int mi = 0; mi < 3; ++mi)
            #pragma unroll
            for (int ni = 0; ni < 4; ++ni) acc[mi][ni] = zero;

        for (int k0 = 0; k0 < CC; k0 += 32) {
            bf16x8 afr[3];
            #pragma unroll
            for (int mi = 0; mi < 3; ++mi)
                afr[mi] = *(const bf16x8*)(W + (size_t)(obase + mi * 16 + l16) * CC + k0 + quad * 8);
            #pragma unroll
            for (int ni = 0; ni < 4; ++ni) {
                bf16x8 bfr = *(const bf16x8*)&xT[ni * 16 + l16][k0 + quad * 8];
                #pragma unroll
                for (int mi = 0; mi < 3; ++mi)
                    acc[mi][ni] = MFMA16(afr[mi], bfr, acc[mi][ni]);
            }
        }

        bf16_t* dst = (og < 2) ? qT : kT;
        #pragma unroll
        for (int mi = 0; mi < 3; ++mi)
            #pragma unroll
            for (int ni = 0; ni < 4; ++ni) {
                const int o0 = obase + mi * 16 + quad * 4;
                const int tl = t0 + ni * 16 + l16;
                U2 lo2, hi2;
                lo2.h[0] = (bf16_t)acc[mi][ni][0]; lo2.h[1] = (bf16_t)acc[mi][ni][1];
                hi2.h[0] = (bf16_t)acc[mi][ni][2]; hi2.h[1] = (bf16_t)acc[mi][ni][3];
                uint2 pk; pk.x = lo2.u; pk.y = hi2.u;
                *(uint2*)(dst + ((size_t)b * TT + tl) * CC + o0) = pk;
            }
    } else {
        f32x4 acc[4][3];
        const f32x4 zero = {0.f, 0.f, 0.f, 0.f};
        #pragma unroll
        for (int mi = 0; mi < 4; ++mi)
            #pragma unroll
            for (int ni = 0; ni < 3; ++ni) acc[mi][ni] = zero;

        for (int k0 = 0; k0 < CC; k0 += 32) {
            bf16x8 bfr[3];
            #pragma unroll
            for (int ni = 0; ni < 3; ++ni)
                bfr[ni] = *(const bf16x8*)(W + (size_t)(obase + ni * 16 + l16) * CC + k0 + quad * 8);
            #pragma unroll
            for (int mi = 0; mi < 4; ++mi) {
                bf16x8 afr = *(const bf16x8*)&xT[mi * 16 + l16][k0 + quad * 8];
                #pragma unroll
                for (int ni = 0; ni < 3; ++ni)
                    acc[mi][ni] = MFMA16(afr, bfr[ni], acc[mi][ni]);
            }
        }

        #pragma unroll
        for (int mi = 0; mi < 4; ++mi)
            #pragma unroll
            for (int ni = 0; ni < 3; ++ni) {
                const int ol  = obase + ni * 16 + l16;
                const int tl0 = mi * 16 + quad * 4;
                U2 lo2, hi2;
                lo2.h[0] = (bf16_t)acc[mi][ni][0]; lo2.h[1] = (bf16_t)acc[mi][ni][1];
                hi2.h[0] = (bf16_t)acc[mi][ni][2]; hi2.h[1] = (bf16_t)acc[mi][ni][3];
                uint2 pk; pk.x = lo2.u; pk.y = hi2.u;
                *(uint2*)(vm + ((size_t)b * CC + ol) * TT + t0 + tl0) = pk;
            }

        #pragma unroll
        for (int ni = 0; ni < 3; ++ni) {
            float s = 0.f;
            #pragma unroll
            for (int mi = 0; mi < 4; ++mi)
                #pragma unroll
                for (int r = 0; r < 4; ++r) s += acc[mi][ni][r];
            s += __shfl_xor(s, 16, 64);
            s += __shfl_xor(s, 32, 64);
            if (quad == 0)
                atomicAdd(&vrs[b * CC + obase + ni * 16 + l16], s);
        }
    }
}

// ---------------------------------------------------------------------------
// K2: fused attention. Grid 512 = 8 b (XCD) x 16 q-tiles(64q) x 4 t-quarters.
// 256 thr / 4 waves (no-spill config, 256 VGPR). Round-9 changes:
//  - Ks DOUBLE-buffered (LDS 72 KB -> still 2 blocks/CU at 144 KB): K(t+1)
//    issued at tile TOP gets the whole scores+mix phase (~2K cy) to land,
//    removing the B2 drain stall.
//  - STAGGER: odd-rr blocks start the (commutative) tile loop 4 tiles in,
//    de-phasing the 2 co-resident blocks so one's VALU mix overlaps the
//    other's MFMA/staging (round-8 VALUBusy 28% = lockstep signature).
//  - s_setprio(1) around MFMA clusters.
//  - regular (cached) stores so proj's partial reads hit L2/L3.
// ---------------------------------------------------------------------------
__global__ __launch_bounds__(256, 1) void fused_attn(
    const bf16_t* __restrict__ qT,
    const bf16_t* __restrict__ kT,
    const bf16_t* __restrict__ vm,
    const float*  __restrict__ head_w,
    float* __restrict__ Up,      // [4][8][6][1024][64]
    float* __restrict__ lp,      // [4][48][1024]
    float* __restrict__ l2p)     // [4][48][1024]
{
    const int L  = blockIdx.x;
    const int b  = L & 7;              // XCD-pinned
    const int rr = L >> 3;
    const int qt = rr & 15;            // 0..15 (64-q tile)
    const int tq = rr >> 4;            // 0..3  (256-t quarter)
    const int T0 = tq * 256;
    const int stag = (rr & 1) * 4;     // de-phase co-resident blocks

    const int tid = threadIdx.x, lane = tid & 63, wid = tid >> 6;
    const int quad = lane >> 4, l16 = lane & 15;

    __shared__ __align__(16) bf16_t sm[36864];   // 72 KB: Ks0|Ks1 (2x24K) | Vs 24K
    const int  s3    = l16 & 7;
    const int  vswz  = (quad ^ ((l16 >> 1) & 3)) * 8;
    const int  addrA = ((quad & 1) * 32 + l16) * 4;
    const int  addrB = addrA + 64;
    const bool qlo   = (quad < 2);

    // mix coefficients -> SGPRs
    float mixc[36];
    #pragma unroll
    for (int j = 0; j < 36; ++j) {
        const float v = 0.125f * head_w[j];
        mixc[j] = __uint_as_float(__builtin_amdgcn_readfirstlane(__float_as_uint(v)));
    }

    // persistent Q fragments: rows q = qt*64 + wid*16 + l16
    bf16x8 qf[6][2];
    {
        const bf16_t* qp = qT + ((size_t)b * TT + qt * 64 + wid * 16 + l16) * CC + quad * 8;
        #pragma unroll
        for (int h = 0; h < 6; ++h)
            #pragma unroll
            for (int k2 = 0; k2 < 2; ++k2)
                qf[h][k2] = *(const bf16x8*)(qp + h * 64 + k2 * 32);
    }

    // staging: pre-swizzled global src, linear LDS dst. 1536 chunks per buf.
    int koff[6], voff[6];
    #pragma unroll
    for (int i = 0; i < 6; ++i) {
        const int f = i * 256 + tid;
        const int krow = f / 48, kc = f - krow * 48;           // Ks: 32 rows x 48 chunks
        koff[i] = krow * CC + ((kc & 56) | ((kc ^ krow) & 7)) * 8;
        const int vrow = f >> 2, vc = f & 3;                   // Vs: 384 rows x 4 chunks
        voff[i] = vrow * TT + ((vc ^ ((vrow >> 1) & 3)) * 8);
    }
    const bf16_t* kTb = kT + ((size_t)b * TT + T0) * CC;
    const bf16_t* vmb = vm + (size_t)b * CC * TT + T0;
    char* KsB = (char*)sm;             // Ks buf p at byte p*24576
    char* VsB = (char*)sm + 49152;     // elem offset 24576
    const int ldst = tid * 16;

    // prologue: stage K(lt=stag) into buf 0
    #pragma unroll
    for (int i = 0; i < 6; ++i)
        gload_lds16(kTb + (size_t)stag * 32 * CC + koff[i], KsB + i * 4096 + ldst);

    f32x4 U[6][4];
    const f32x4 zero = {0.f, 0.f, 0.f, 0.f};
    #pragma unroll
    for (int h = 0; h < 6; ++h)
        #pragma unroll
        for (int d = 0; d < 4; ++d) U[h][d] = zero;
    float lacc[6]  = {0.f, 0.f, 0.f, 0.f, 0.f, 0.f};
    float l2acc[6] = {0.f, 0.f, 0.f, 0.f, 0.f, 0.f};

    __syncthreads();   // K buf0 staged

    for (int it = 0; it < 8; ++it) {
        const int lt = (it + stag) & 7;    // logical tile (exact sum: any order)
        const int cb = it & 1;             // current K buffer

        // ---- issue V(lt) and K(next) at tile top (both land during scores+mix)
        #pragma unroll
        for (int i = 0; i < 6; ++i)
            gload_lds16(vmb + lt * 32 + voff[i], VsB + i * 4096 + ldst);
        if (it < 7) {
            const int ltn = (lt + 1) & 7;
            #pragma unroll
            for (int i = 0; i < 6; ++i)
                gload_lds16(kTb + (size_t)ltn * 32 * CC + koff[i],
                            KsB + (cb ^ 1) * 24576 + i * 4096 + ldst);
        }

        // ---- per-head scores: lane (q = l16, t = blk*16 + quad*4 + r)
        const bf16_t* Kc = sm + cb * 12288;
        f32x4 S[6][2];
        __builtin_amdgcn_s_setprio(1);
        #pragma unroll
        for (int h = 0; h < 6; ++h) {
            #pragma unroll
            for (int blk = 0; blk < 2; ++blk) {
                const bf16_t* Ar = Kc + (size_t)(blk * 16 + l16) * CC + h * 64;
                bf16x8 a0 = *(const bf16x8*)(Ar + ((quad ^ s3) * 8));
                bf16x8 a1 = *(const bf16x8*)(Ar + (((4 + quad) ^ s3) * 8));
                f32x4 s = MFMA16(a0, qf[h][0], zero);
                S[h][blk] = MFMA16(a1, qf[h][1], s);
            }
        }
        __builtin_amdgcn_s_setprio(0);

        // ---- mix + exp + l/l2 + intra-wave transpose -> PV A-frags
        bf16x8 pa[6];
        #pragma unroll
        for (int g = 0; g < 6; ++g) {
            unsigned int uu[2][2];
            #pragma unroll
            for (int blk = 0; blk < 2; ++blk) {
                f32x4 m = mixc[g * 6] * S[0][blk];
                #pragma unroll
                for (int h2 = 1; h2 < 6; ++h2) m += mixc[g * 6 + h2] * S[h2][blk];
                f32x4 pv;
                #pragma unroll
                for (int r = 0; r < 4; ++r) pv[r] = __expf(fminf(m[r], 60.0f));
                lacc[g]  += pv[0] + pv[1] + pv[2] + pv[3];
                l2acc[g] += pv[0] * pv[0] + pv[1] * pv[1] + pv[2] * pv[2] + pv[3] * pv[3];
                U2 lo, hi;
                lo.h[0] = (bf16_t)pv[0]; lo.h[1] = (bf16_t)pv[1];
                hi.h[0] = (bf16_t)pv[2]; hi.h[1] = (bf16_t)pv[3];
                uu[blk][0] = lo.u; uu[blk][1] = hi.u;
            }
            int x0 = __builtin_amdgcn_ds_bpermute(addrA, (int)uu[0][0]);
            int y0 = __builtin_amdgcn_ds_bpermute(addrA, (int)uu[1][0]);
            int x1 = __builtin_amdgcn_ds_bpermute(addrA, (int)uu[0][1]);
            int y1 = __builtin_amdgcn_ds_bpermute(addrA, (int)uu[1][1]);
            int x2 = __builtin_amdgcn_ds_bpermute(addrB, (int)uu[0][0]);
            int y2 = __builtin_amdgcn_ds_bpermute(addrB, (int)uu[1][0]);
            int x3 = __builtin_amdgcn_ds_bpermute(addrB, (int)uu[0][1]);
            int y3 = __builtin_amdgcn_ds_bpermute(addrB, (int)uu[1][1]);
            I4B c;
            c.i = (i32x4){qlo ? x0 : y0, qlo ? x1 : y1, qlo ? x2 : y2, qlo ? x3 : y3};
            pa[g] = c.v;
        }

        __syncthreads();   // B1: drains V(lt) + K(next); all Ks[cb] reads done

        // ---- PV: U[q][d] += P[q][t] * V[d][t] over the 32-t tile
        const bf16_t* Vb = sm + 24576;
        __builtin_amdgcn_s_setprio(1);
        #pragma unroll
        for (int h = 0; h < 6; ++h) {
            #pragma unroll
            for (int n2 = 0; n2 < 4; ++n2) {
                bf16x8 bv = *(const bf16x8*)(Vb + (size_t)(h * 64 + n2 * 16 + l16) * 32 + vswz);
                U[h][n2] = MFMA16(pa[h], bv, U[h][n2]);
            }
        }
        __builtin_amdgcn_s_setprio(0);

        __syncthreads();   // B2: Vs reads done (vmcnt already 0 -> cheap)
    }

    // ---- epilogue: direct per-wave outputs
    #pragma unroll
    for (int g = 0; g < 6; ++g) {
        float l = lacc[g], l2 = l2acc[g];
        l  += __shfl_xor(l, 16, 64);  l  += __shfl_xor(l, 32, 64);
        l2 += __shfl_xor(l2, 16, 64); l2 += __shfl_xor(l2, 32, 64);
        if (quad == 0) {
            const size_t o = ((size_t)tq * 48 + b * 6 + g) * TT + qt * 64 + wid * 16 + l16;
            lp[o] = l; l2p[o] = l2;
        }
    }

    #pragma unroll
    for (int h = 0; h < 6; ++h) {
        float* Ub = Up + ((((size_t)tq * 8 + b) * 6 + h) * TT + qt * 64 + wid * 16) * 64;
        #pragma unroll
        for (int n2 = 0; n2 < 4; ++n2)
            #pragma unroll
            for (int r = 0; r < 4; ++r)
                Ub[(size_t)(quad * 4 + r) * 64 + n2 * 16 + l16] = U[h][n2][r];
    }
}

// ---------------------------------------------------------------------------
// K2b: merge 4 t-quarter partials. Grid 192 = 48 bg x 4 q-chunks; sq via
// atomics (sq memset in launch).
// ---------------------------------------------------------------------------
__global__ __launch_bounds__(256) void stats_kernel(
    const float* __restrict__ lp, const float* __restrict__ l2p,
    float* __restrict__ linv, float* __restrict__ sq)
{
    const int bg = blockIdx.x >> 2;
    const int q  = (blockIdx.x & 3) * 256 + threadIdx.x;
    const int tid = threadIdx.x;
    const float l  = lp [(size_t)bg * TT + q] + lp [(size_t)(48 + bg) * TT + q]
                   + lp [(size_t)(96 + bg) * TT + q] + lp [(size_t)(144 + bg) * TT + q];
    const float l2 = l2p[(size_t)bg * TT + q] + l2p[(size_t)(48 + bg) * TT + q]
                   + l2p[(size_t)(96 + bg) * TT + q] + l2p[(size_t)(144 + bg) * TT + q];
    const float inv = 1.0f / l;
    linv[bg * TT + q] = inv;
    float c = l2 * inv * inv;
    #pragma unroll
    for (int off = 1; off < 64; off <<= 1) c += __shfl_xor(c, off, 64);
    __shared__ float red[4];
    if ((tid & 63) == 0) red[tid >> 6] = c;
    __syncthreads();
    if (tid == 0) atomicAdd(&sq[bg], red[0] + red[1] + red[2] + red[3]);
}

// ---------------------------------------------------------------------------
// K3: projection + fused InstanceNorm affine + bias + transpose.
// bf16 projW (castw), regular (cached) partial loads — L3 absorbs the 50 MB.
// Grid (64,8): 16-t tiles -> 512 blocks = 2 blocks/CU.
// ---------------------------------------------------------------------------
__global__ __launch_bounds__(256) void proj_kernel(
    const float* __restrict__ Up,
    const float* __restrict__ linv,
    const float* __restrict__ vrs,
    const float* __restrict__ sumsq,
    const float* __restrict__ gamma,
    const float* __restrict__ beta,
    const bf16_t* __restrict__ projW,
    const float* __restrict__ projb,
    float* __restrict__ out)
{
    const int ts = blockIdx.x;
    const int b  = blockIdx.y;
    const int t0 = ts * 16;
    const int tid = threadIdx.x, lane = tid & 63, wid = tid >> 6;
    const int quad = lane >> 4, l16 = lane & 15;

    __shared__ float Ac[6], Cc[6], pb[CC];
    if (tid < 6) {
        const float ss  = sumsq[b * NHH + tid];
        const float var = fmaxf(ss - 1.0f, 0.0f) * (1.0f / 1048576.0f);
        const float a   = gamma[tid] * rsqrtf(var + 1e-5f);
        Ac[tid] = a;
        Cc[tid] = beta[tid] - a * (1.0f / 1024.0f);
    }
    for (int i = tid; i < CC; i += 256) pb[i] = projb[i];
    __syncthreads();

    f32x4 acc[6];
    const f32x4 zero = {0.f, 0.f, 0.f, 0.f};
    #pragma unroll
    for (int mi = 0; mi < 6; ++mi) acc[mi] = zero;

    constexpr size_t PST = (size_t)BB * NHH * TT * 64;
    const float* Ub = Up + (size_t)b * (NHH * TT * 64);
    for (int k0 = 0; k0 < CC; k0 += 32) {
        const int tl = t0 + l16;
        const int baseoff = tl * CC + k0 + quad * 8;
        const int hh = baseoff >> 16;                 // constant over j (8-aligned)
        const int d0 = baseoff & 63;                  // d of j=0; d0+7 <= 63
        const float li = linv[b * 6144 + (baseoff >> 6)];
        const float Al = Ac[hh] * li;
        const float Cb = Cc[hh];
        f32x4 u0 = *(const f32x4*)(Ub + baseoff)
                 + *(const f32x4*)(Ub + PST + baseoff)
                 + *(const f32x4*)(Ub + 2 * PST + baseoff)
                 + *(const f32x4*)(Ub + 3 * PST + baseoff);
        f32x4 u1 = *(const f32x4*)(Ub + baseoff + 4)
                 + *(const f32x4*)(Ub + PST + baseoff + 4)
                 + *(const f32x4*)(Ub + 2 * PST + baseoff + 4)
                 + *(const f32x4*)(Ub + 3 * PST + baseoff + 4);
        U8 z;
        #pragma unroll
        for (int j = 0; j < 8; ++j) {
            const float uv = (j < 4) ? u0[j] : u1[j - 4];
            z.h[j] = (bf16_t)(Al * uv + Cb * vrs[b * CC + hh * 64 + d0 + j]);
        }
        bf16x8 bfr = *(const bf16x8*)&z;
        #pragma unroll
        for (int mi = 0; mi < 6; ++mi) {
            const int o = wid * 96 + mi * 16 + l16;
            bf16x8 afr = *(const bf16x8*)(projW + (size_t)o * CC + k0 + quad * 8);
            acc[mi] = MFMA16(afr, bfr, acc[mi]);
        }
    }

    #pragma unroll
    for (int mi = 0; mi < 6; ++mi)
        #pragma unroll
        for (int r = 0; r < 4; ++r) {
            const int o  = wid * 96 + mi * 16 + quad * 4 + r;
            const int tl = t0 + l16;
            out[((size_t)b * CC + o) * TT + tl] = acc[mi][r] + pb[o];
        }
}

// ---------------------------------------------------------------------------
extern "C" void kernel_launch(void* const* d_in, const int* in_sizes, int n_in,
                              void* d_out, int out_size, void* d_ws, size_t ws_size,
                              hipStream_t stream)
{
    float* outp = (float*)d_out;
    char* ws = (char*)d_ws;

    size_t off = 0;
    auto alloc = [&](size_t bytes) {
        void* p = ws + off;
        off += (bytes + 255) & ~(size_t)255;
        return p;
    };

    const size_t szT = (size_t)BB * TT * CC * sizeof(bf16_t);   // 6.29 MB
    const size_t szW = (size_t)CC * CC * sizeof(bf16_t);        // 288 KB

    bf16_t* qTb = (bf16_t*)alloc(szT);
    bf16_t* kTb = (bf16_t*)alloc(szT);
    bf16_t* vmb = (bf16_t*)alloc(szT);
    bf16_t* Wqb = (bf16_t*)alloc(szW);
    bf16_t* Wkb = (bf16_t*)alloc(szW);
    bf16_t* Wvb = (bf16_t*)alloc(szW);
    bf16_t* PWb = (bf16_t*)alloc(szW);
    float*  Uh  = (float*)alloc((size_t)4 * BB * NHH * TT * 64 * sizeof(float)); // 50.3 MB
    float*  lpb = (float*)alloc((size_t)4 * 48 * TT * sizeof(float));
    float*  l2b = (float*)alloc((size_t)4 * 48 * TT * sizeof(float));
    float*  lv  = (float*)alloc((size_t)48 * TT * sizeof(float));
    float*  vr  = (float*)alloc((size_t)BB * CC * sizeof(float));
    float*  sq  = (float*)alloc(48 * sizeof(float));

    hipMemsetAsync(vr, 0, (size_t)BB * CC * sizeof(float), stream);
    hipMemsetAsync(sq, 0, 48 * sizeof(float), stream);
    castw_kernel<<<dim3(72, 4), 256, 0, stream>>>(
        (const float*)d_in[1], (const float*)d_in[2], (const float*)d_in[3],
        (const float*)d_in[7], Wqb, Wkb, Wvb, PWb);
    qkv_kernel<<<dim3(16, 6, 8), 256, 0, stream>>>(
        (const float*)d_in[0], Wqb, Wkb, Wvb, qTb, kTb, vmb, vr);
    fused_attn<<<512, 256, 0, stream>>>(
        qTb, kTb, vmb, (const float*)d_in[4], Uh, lpb, l2b);
    stats_kernel<<<192, 256, 0, stream>>>(lpb, l2b, lv, sq);
    proj_kernel<<<dim3(64, 8), 256, 0, stream>>>(
        Uh, lv, vr, sq, (const float*)d_in[5], (const float*)d_in[6],
        PWb, (const float*)d_in[8], outp);
}